// Round 7
// baseline (873.227 us; speedup 1.0000x reference)
//
#include <hip/hip_runtime.h>

// TopK-and-scatter: out[r,c] = x[r,c] if x[r,c] is among the top-64 of row r
// (ties at threshold broken by LOWEST column index, matching lax.top_k), else 0.
// R7: software-pipelined rows with ZERO extra VGPRs. Next row is prefetched
// into a 128 KB LDS buffer via global_load_lds (no register staging); with the
// linear chunk layout each wave reads back exactly the bytes its own loads
// wrote, so the row buffer is wave-private: no barriers for it, just a counted
// s_waitcnt vmcnt(8) at the top of each iteration (8 = the previous row's
// stores still in flight). All select-phase barriers are lgkm-only raw
// s_barrier, so prefetch loads stay in flight through select+write.
// Select per row: positive-only 12-bit histogram (bits [30:19]) -> suffix scan
// -> crossing-bin candidate list -> per-thread exact composite rank
// (key desc, col asc). Exact bitwise-search slow path for pathological rows.

typedef float f32x4 __attribute__((ext_vector_type(4)));
typedef unsigned int u32;
typedef u32 u32x4 __attribute__((ext_vector_type(4)));

#define TPB   1024
#define COLS  32768
#define EPT   32
#define KSEL  64u
#define CAP   1984u
#define RPB   32

// LDS-only barrier: orders LDS ops across the block WITHOUT draining vmcnt.
__device__ __forceinline__ void ldsBarrier() {
    asm volatile("s_waitcnt lgkmcnt(0)" ::: "memory");
    __builtin_amdgcn_s_barrier();
    asm volatile("" ::: "memory");
}

// Issue one row (128 KB) of global->LDS loads. Chunk j, wave w: LDS dest base
// (j*1024 + w*64) f32x4 slots (wave-uniform); HW adds lane*16. Global source
// is per-lane. Each wave's lanes later read exactly the slots they wrote.
__device__ __forceinline__ void issueRowLoads(const float* __restrict__ rowBase,
                                              u32* rowbuf, int wid, int lane)
{
    #pragma unroll
    for (int j = 0; j < 8; ++j) {
        const int vidx = j * TPB + wid * 64 + lane;          // f32x4 units
        const float* gp = rowBase + (size_t)vidx * 4;
        u32* lp = rowbuf + (size_t)(j * TPB + wid * 64) * 4; // wave-uniform
        __builtin_amdgcn_global_load_lds(
            (const __attribute__((address_space(1))) void*)gp,
            (__attribute__((address_space(3))) void*)lp, 16, 0, 0);
    }
}

__device__ __forceinline__ u32 blockSum(u32 v, u32* wtot, int lane, int wid)
{
    #pragma unroll
    for (int off = 32; off >= 1; off >>= 1) v += __shfl_down(v, off);
    if (lane == 0) wtot[wid] = v;
    __syncthreads();
    u32 t = 0;
    #pragma unroll
    for (int w = 0; w < 16; ++w) t += wtot[w];
    __syncthreads();
    return t;
}

__global__ __launch_bounds__(TPB) void topk_scatter_kernel(
    const float* __restrict__ x, float* __restrict__ out, int totalRows)
{
    __shared__ u32 rowbuf[COLS];          // 131072 B
    __shared__ u32 hist[4096];            //  16384 B
    __shared__ u32 candKey[CAP];          //   7936 B
    __shared__ u32 candCol[CAP];          //   7936 B
    __shared__ u32 wtot[16];
    __shared__ int sBin;
    __shared__ u32 sAbove;
    __shared__ u32 candN;

    const int tid  = threadIdx.x;
    const int lane = tid & 63;
    const int wid  = tid >> 6;
    const int r0   = blockIdx.x * RPB;
    if (r0 >= totalRows) return;

    // ---- prologue: zero hist, issue row r0 prefetch ----
    ((u32x4*)hist)[tid] = (u32x4)(0u);
    if (tid == 0) { sBin = -1; candN = 0u; }
    issueRowLoads(x + (long long)r0 * COLS, rowbuf, wid, lane);
    ldsBarrier();                                      // hist zeros visible

    #pragma unroll 1
    for (int i = 0; i < RPB; ++i) {
        const int row = r0 + i;
        if (row >= totalRows) break;                   // block-uniform

        // ---- wait own prefetch (8 newest outstanding = prev row's stores) ----
        if (i == 0) { asm volatile("s_waitcnt vmcnt(0)" ::: "memory"); }
        else        { asm volatile("s_waitcnt vmcnt(8)" ::: "memory"); }
        __builtin_amdgcn_sched_barrier(0);

        // ---- read rowbuf -> keys (wave-private region) ----
        u32 key[EPT];
        #pragma unroll
        for (int j = 0; j < 8; ++j) {
            const u32x4 rv = ((const u32x4*)rowbuf)[j * TPB + tid];
            #pragma unroll
            for (int l = 0; l < 4; ++l) {
                const u32 b = rv[l];
                key[j * 4 + l] = b ^ ((u32)((int)b >> 31) | 0x80000000u);
            }
        }
        // my reads done -> safe to issue overwriting prefetch (wave-private)
        asm volatile("s_waitcnt lgkmcnt(0)" ::: "memory");
        __builtin_amdgcn_sched_barrier(0);
        if (i + 1 < RPB && row + 1 < totalRows)
            issueRowLoads(x + (long long)(row + 1) * COLS, rowbuf, wid, lane);

        if (tid == 0) { sBin = -1; candN = 0u; }       // >=3 barriers from readers

        // ---- positive-only histogram: bins = bits [30:19] ----
        #pragma unroll
        for (int e = 0; e < EPT; ++e) {
            const u32 k = key[e];
            if (k & 0x80000000u) atomicAdd(&hist[(k & 0x7fffffffu) >> 19], 1u);
        }
        ldsBarrier();                                  // B2: hist complete

        // ---- suffix scan; thread owns bins [4*tid,4*tid+4); zero after read ----
        u32 need = KSEL;
        {
            const u32x4 h = ((const u32x4*)hist)[tid];
            ((u32x4*)hist)[tid] = (u32x4)(0u);         // ready for next row
            const u32 ls3 = h[3];
            const u32 ls2 = h[2] + ls3;
            const u32 ls1 = h[1] + ls2;
            const u32 ls0 = h[0] + ls1;
            u32 v = ls0;
            #pragma unroll
            for (int off = 1; off < 64; off <<= 1) {
                const u32 t = __shfl_down(v, off);
                if (lane + off < 64) v += t;
            }
            if (lane == 0) wtot[wid] = v;
            ldsBarrier();                              // B3: wtot ready
            u32 tailWaves = 0u;
            for (int w = wid + 1; w < 16; ++w) tailWaves += wtot[w];
            const u32 thrTail = tailWaves + (v - ls0);
            const u32 S0 = ls0 + thrTail, S1 = ls1 + thrTail, S2 = ls2 + thrTail,
                      S3 = ls3 + thrTail, S4 = thrTail;
            if (S0 >= need && S1 < need) { sBin = 4 * tid + 0; sAbove = S1; }
            if (S1 >= need && S2 < need) { sBin = 4 * tid + 1; sAbove = S2; }
            if (S2 >= need && S3 < need) { sBin = 4 * tid + 2; sAbove = S3; }
            if (S3 >= need && S4 < need) { sBin = 4 * tid + 3; sAbove = S4; }
            ldsBarrier();                              // B4: crossing known
        }
        const int b1s = sBin;                          // snapshot immediately
        const u32 above = sAbove;
        bool fast = (b1s >= 0);
        u32 b1 = 0, C = 0;

        if (fast) {
            b1 = (u32)b1s;
            need = KSEL - above;                       // 1 <= need <= count(b1)
            #pragma unroll
            for (int e = 0; e < EPT; ++e) {
                const u32 k = key[e];
                if ((k & 0x80000000u) && ((k & 0x7fffffffu) >> 19) == b1) {
                    const u32 p = atomicAdd(&candN, 1u);
                    if (p < CAP) {
                        candKey[p] = k;
                        candCol[p] = (u32)(((e >> 2) * TPB + tid) * 4 + (e & 3));
                    }
                }
            }
            ldsBarrier();                              // B5: candidates ready
            C = candN;                                 // snapshot immediately
            fast = (C <= CAP);
        }

        f32x4* __restrict__ orow = (f32x4*)(out + (long long)row * COLS);

        if (fast) {
            // ---- fused write: per-thread exact rank for own b1 elements ----
            #pragma unroll
            for (int j = 0; j < 8; ++j) {
                f32x4 o;
                #pragma unroll
                for (int l = 0; l < 4; ++l) {
                    const u32 k = key[j * 4 + l];
                    bool sel = false;
                    if (k & 0x80000000u) {
                        const u32 kb = (k & 0x7fffffffu) >> 19;
                        if (kb > b1) sel = true;
                        else if (kb == b1) {
                            const u32 col = (u32)((j * TPB + tid) * 4 + l);
                            u32 r = 0;
                            for (u32 q = 0; q < C; ++q) {   // LDS broadcast
                                const u32 kq = candKey[q];
                                r += (kq > k || (kq == k && candCol[q] < col))
                                         ? 1u : 0u;
                            }
                            sel = (r < need);
                        }
                    }
                    o[l] = sel ? __uint_as_float(k ^ 0x80000000u) : 0.0f;
                }
                orow[j * TPB + tid] = o;
            }
        } else {
            // ---- exact slow path (any input): bitwise searches ----
            u32 pfx = 0u;
            for (int bit = 31; bit >= 0; --bit) {
                const u32 trial = pfx | (1u << bit);
                u32 loc = 0u;
                #pragma unroll
                for (int e = 0; e < EPT; ++e) loc += (key[e] >= trial) ? 1u : 0u;
                if (blockSum(loc, wtot, lane, wid) >= KSEL) pfx = trial;
            }
            const u32 T = pfx;                         // 64th largest key
            u32 loc = 0u;
            #pragma unroll
            for (int e = 0; e < EPT; ++e) loc += (key[e] > T) ? 1u : 0u;
            const u32 needEq = KSEL - blockSum(loc, wtot, lane, wid);
            u32 cv = 0u;
            for (int bit = 14; bit >= 0; --bit) {
                const u32 trial = cv | (1u << bit);
                u32 l2 = 0u;
                #pragma unroll
                for (int e = 0; e < EPT; ++e) {
                    const u32 col = (u32)(((e >> 2) * TPB + tid) * 4 + (e & 3));
                    l2 += (key[e] == T && col < trial) ? 1u : 0u;
                }
                if (blockSum(l2, wtot, lane, wid) < needEq) cv = trial;
            }
            const u32 colT = cv;
            #pragma unroll
            for (int j = 0; j < 8; ++j) {
                f32x4 o;
                #pragma unroll
                for (int l = 0; l < 4; ++l) {
                    const u32 k = key[j * 4 + l];
                    const u32 col = (u32)((j * TPB + tid) * 4 + l);
                    const bool sel = (k > T) || (k == T && col <= colT);
                    const float val =
                        __uint_as_float((k & 0x80000000u) ? (k ^ 0x80000000u) : ~k);
                    o[l] = sel ? val : 0.0f;
                }
                orow[j * TPB + tid] = o;
            }
        }
    }
}

extern "C" void kernel_launch(void* const* d_in, const int* in_sizes, int n_in,
                              void* d_out, int out_size, void* d_ws, size_t ws_size,
                              hipStream_t stream)
{
    (void)n_in; (void)out_size; (void)d_ws; (void)ws_size;
    const float* x = (const float*)d_in[0];
    float* out = (float*)d_out;
    const int rows = in_sizes[0] / COLS;
    const int grid = (rows + RPB - 1) / RPB;
    topk_scatter_kernel<<<dim3(grid), dim3(TPB), 0, stream>>>(x, out, rows);
}

// Round 8
// 461.220 us; speedup vs baseline: 1.8933x; 1.8933x over previous
//
#include <hip/hip_runtime.h>

// TopK-and-scatter: out[r,c] = x[r,c] if x[r,c] is among the top-64 of row r
// (ties at threshold broken by LOWEST column index, matching lax.top_k), else 0.
// R8 = R5 chassis (one row per 1024-thread block, 2 blocks/CU, loads->regs,
// positive-only 4096-bin histogram, shuffle suffix scan) with select cost cut:
// fused-rank write (no T/colT broadcast passes; 5 barriers total) and packed
// u64 candidates ((key<<32)|~col) so the rank loop is one ds_read_b64/cand.
// Exact bitwise-search slow path (block-uniform) for pathological rows.

typedef float f32x4 __attribute__((ext_vector_type(4)));
typedef unsigned int u32;
typedef unsigned long long u64;
typedef u32 u32x4 __attribute__((ext_vector_type(4)));

#define TPB   1024
#define COLS  32768
#define EPT   32
#define KSEL  64u
#define CAP   2048u

__device__ __forceinline__ u32 blockSum(u32 v, u32* wtot, int lane, int wid)
{
    #pragma unroll
    for (int off = 32; off >= 1; off >>= 1) v += __shfl_down(v, off);
    if (lane == 0) wtot[wid] = v;
    __syncthreads();
    u32 t = 0;
    #pragma unroll
    for (int w = 0; w < 16; ++w) t += wtot[w];
    __syncthreads();
    return t;
}

__global__ __launch_bounds__(TPB) void topk_scatter_kernel(
    const float* __restrict__ x, float* __restrict__ out)
{
    __shared__ u32 hist[4096];            // 16 KB
    __shared__ u64 candPk[CAP];           // 16 KB
    __shared__ u32 wtot[16];
    __shared__ int sBin;
    __shared__ u32 sAbove;
    __shared__ u32 candN;

    const int tid  = threadIdx.x;
    const int lane = tid & 63;
    const int wid  = tid >> 6;

    const long long row = blockIdx.x;
    const f32x4* __restrict__ xrow = (const f32x4*)(x + row * (long long)COLS);
    f32x4* __restrict__ orow       = (f32x4*)(out + row * (long long)COLS);

    // zero histogram + counters (ordered by barrier A)
    ((u32x4*)hist)[tid] = (u32x4)(0u);
    if (tid == 0) { sBin = -1; candN = 0u; }

    // ---- load row into registers (8 loads in flight, no LDS deps) ----
    u32 key[EPT];
    #pragma unroll
    for (int j = 0; j < 8; ++j) {
        const f32x4 v = xrow[j * TPB + tid];
        #pragma unroll
        for (int l = 0; l < 4; ++l) {
            const u32 b = __float_as_uint(v[l]);
            key[j * 4 + l] = b ^ ((u32)((int)b >> 31) | 0x80000000u);
        }
    }
    __syncthreads();                                   // A: zeros visible

    // ---- positive-only histogram: bins = bits [30:19] ----
    #pragma unroll
    for (int e = 0; e < EPT; ++e) {
        const u32 k = key[e];
        if (k & 0x80000000u) atomicAdd(&hist[(k & 0x7fffffffu) >> 19], 1u);
    }
    __syncthreads();                                   // B: hist complete

    u32 need = KSEL;

    // ---- suffix scan: thread owns bins [4*tid, 4*tid+4) ----
    {
        const u32x4 h = ((const u32x4*)hist)[tid];
        const u32 ls3 = h[3];
        const u32 ls2 = h[2] + ls3;
        const u32 ls1 = h[1] + ls2;
        const u32 ls0 = h[0] + ls1;
        u32 v = ls0;                                   // wave suffix scan (shfl)
        #pragma unroll
        for (int off = 1; off < 64; off <<= 1) {
            const u32 t = __shfl_down(v, off);
            if (lane + off < 64) v += t;
        }
        if (lane == 0) wtot[wid] = v;
        __syncthreads();                               // C: wtot ready
        u32 tailWaves = 0u;
        for (int w = wid + 1; w < 16; ++w) tailWaves += wtot[w];
        const u32 thrTail = tailWaves + (v - ls0);
        const u32 S0 = ls0 + thrTail, S1 = ls1 + thrTail, S2 = ls2 + thrTail,
                  S3 = ls3 + thrTail, S4 = thrTail;
        if (S0 >= need && S1 < need) { sBin = 4 * tid + 0; sAbove = S1; }
        if (S1 >= need && S2 < need) { sBin = 4 * tid + 1; sAbove = S2; }
        if (S2 >= need && S3 < need) { sBin = 4 * tid + 2; sAbove = S3; }
        if (S3 >= need && S4 < need) { sBin = 4 * tid + 3; sAbove = S4; }
        __syncthreads();                               // D: crossing known
    }
    const int b1s = sBin;                              // snapshot
    const u32 above = sAbove;
    bool fast = (b1s >= 0);
    u32 b1 = 0, C = 0;

    if (fast) {
        b1 = (u32)b1s;
        need = KSEL - above;                           // 1 <= need <= count(b1)
        // ---- collect crossing-bin candidates, packed (key desc, col asc) ----
        #pragma unroll
        for (int e = 0; e < EPT; ++e) {
            const u32 k = key[e];
            if ((k & 0x80000000u) && ((k & 0x7fffffffu) >> 19) == b1) {
                const u32 p = atomicAdd(&candN, 1u);
                if (p < CAP) {
                    const u32 col = (u32)(((e >> 2) * TPB + tid) * 4 + (e & 3));
                    candPk[p] = ((u64)k << 32) | (u32)(~col);
                }
            }
        }
        __syncthreads();                               // E: candidates ready
        C = candN;                                     // snapshot
        fast = (C <= CAP);
    }

    if (fast) {
        // ---- fused write: per-thread exact rank for own b1 elements ----
        #pragma unroll
        for (int j = 0; j < 8; ++j) {
            f32x4 o;
            #pragma unroll
            for (int l = 0; l < 4; ++l) {
                const u32 k = key[j * 4 + l];
                bool sel = false;
                if (k & 0x80000000u) {
                    const u32 kb = (k & 0x7fffffffu) >> 19;
                    if (kb > b1) sel = true;
                    else if (kb == b1) {
                        const u32 col = (u32)((j * TPB + tid) * 4 + l);
                        const u64 me = ((u64)k << 32) | (u32)(~col);
                        u32 r = 0;
                        for (u32 q = 0; q < C; ++q)        // LDS b64 broadcast
                            r += (candPk[q] > me) ? 1u : 0u;
                        sel = (r < need);
                    }
                }
                o[l] = sel ? __uint_as_float(k ^ 0x80000000u) : 0.0f;
            }
            orow[j * TPB + tid] = o;
        }
    } else {
        // ---- exact slow path (any input): bitwise searches ----
        u32 pfx = 0u;
        for (int bit = 31; bit >= 0; --bit) {
            const u32 trial = pfx | (1u << bit);
            u32 loc = 0u;
            #pragma unroll
            for (int e = 0; e < EPT; ++e) loc += (key[e] >= trial) ? 1u : 0u;
            if (blockSum(loc, wtot, lane, wid) >= KSEL) pfx = trial;
        }
        const u32 T = pfx;                             // 64th largest key
        u32 loc = 0u;
        #pragma unroll
        for (int e = 0; e < EPT; ++e) loc += (key[e] > T) ? 1u : 0u;
        const u32 needEq = KSEL - blockSum(loc, wtot, lane, wid);
        u32 cv = 0u;
        for (int bit = 14; bit >= 0; --bit) {
            const u32 trial = cv | (1u << bit);
            u32 l2 = 0u;
            #pragma unroll
            for (int e = 0; e < EPT; ++e) {
                const u32 col = (u32)(((e >> 2) * TPB + tid) * 4 + (e & 3));
                l2 += (key[e] == T && col < trial) ? 1u : 0u;
            }
            if (blockSum(l2, wtot, lane, wid) < needEq) cv = trial;
        }
        const u32 colT = cv;                           // needEq-th smallest eq col
        #pragma unroll
        for (int j = 0; j < 8; ++j) {
            f32x4 o;
            #pragma unroll
            for (int l = 0; l < 4; ++l) {
                const u32 k = key[j * 4 + l];
                const u32 col = (u32)((j * TPB + tid) * 4 + l);
                const bool sel = (k > T) || (k == T && col <= colT);
                const float val =
                    __uint_as_float((k & 0x80000000u) ? (k ^ 0x80000000u) : ~k);
                o[l] = sel ? val : 0.0f;
            }
            orow[j * TPB + tid] = o;
        }
    }
}

extern "C" void kernel_launch(void* const* d_in, const int* in_sizes, int n_in,
                              void* d_out, int out_size, void* d_ws, size_t ws_size,
                              hipStream_t stream)
{
    (void)n_in; (void)out_size; (void)d_ws; (void)ws_size;
    const float* x = (const float*)d_in[0];
    float* out = (float*)d_out;
    const int rows = in_sizes[0] / COLS;
    topk_scatter_kernel<<<dim3(rows), dim3(TPB), 0, stream>>>(x, out);
}